// Round 4
// baseline (166.677 us; speedup 1.0000x reference)
//
#include <hip/hip_runtime.h>
#include <stdint.h>

// HeAttention, MI355X/gfx950 — Round 4: 3 launches.
//   L1 proj: q,k,vT,rkE,rqE projections (as round 3, proven).
//   L2 attn_fused: band-scores + in-register softmax + PV, one block per
//      (h, 64-row i-tile); scores [64x512] held in VGPRs across the j-loop.
//   L3 out = ctx * wo^T + bo (generic BT gemm).
// B=1, S=512, D=512, H=8, hd=64, NE=1024. fp32 I/O, bf16 MFMA internally.

typedef __bf16 bf16_t;
typedef bf16_t bf16x8 __attribute__((ext_vector_type(8)));
typedef float f32x4 __attribute__((ext_vector_type(4)));

__device__ __forceinline__ uint16_t f2bf(float f) {
  union { float f; uint32_t i; } c; c.f = f;
  return (uint16_t)((c.i + 0x7fffu + ((c.i >> 16) & 1u)) >> 16);  // RNE
}
__device__ __forceinline__ uint32_t pack2bf(float lo, float hi) {
  return (uint32_t)f2bf(lo) | ((uint32_t)f2bf(hi) << 16);
}
#define MFMA(a, b, c) __builtin_amdgcn_mfma_f32_16x16x32_bf16((a), (b), (c), 0, 0, 0)

#define LSTR 40   // gemm LDS stride (bf16)
#define SSTR 72   // attn_fused stride (bf16)

// ---------------- generic BT GEMM (out projection) ----------------
__global__ __launch_bounds__(256) void gemm_bt_kernel(
    const void* __restrict__ A, int lda, int zsA, int aF32,
    const void* __restrict__ B, int ldb, int zsB, int bF32,
    const float* __restrict__ bias, int hasBias,
    float* __restrict__ C, int ldc, int zsC, int K)
{
  __shared__ __align__(16) uint16_t As[64 * LSTR];
  __shared__ __align__(16) uint16_t Bs[64 * LSTR];
  const int z = blockIdx.z;
  const int m0 = blockIdx.y * 64, n0 = blockIdx.x * 64;
  const int t = threadIdx.x, lane = t & 63, wave = t >> 6;
  const int wi = wave & 1, wj = wave >> 1;
  const int quad = lane >> 4, l15 = lane & 15;
  const int srow = t >> 2, scol = (t & 3) * 8;

  f32x4 acc[2][2] = {};
  for (int k0 = 0; k0 < K; k0 += 32) {
    uint4 ap, bp;
    if (aF32) {
      const float* Af = (const float*)A + (size_t)z * zsA + (size_t)(m0 + srow) * lda + (k0 + scol);
      float4 x0 = *(const float4*)(Af); float4 x1 = *(const float4*)(Af + 4);
      ap.x = pack2bf(x0.x, x0.y); ap.y = pack2bf(x0.z, x0.w);
      ap.z = pack2bf(x1.x, x1.y); ap.w = pack2bf(x1.z, x1.w);
    } else {
      ap = *(const uint4*)((const uint16_t*)A + (size_t)z * zsA + (size_t)(m0 + srow) * lda + (k0 + scol));
    }
    if (bF32) {
      const float* Bf = (const float*)B + (size_t)z * zsB + (size_t)(n0 + srow) * ldb + (k0 + scol);
      float4 x0 = *(const float4*)(Bf); float4 x1 = *(const float4*)(Bf + 4);
      bp.x = pack2bf(x0.x, x0.y); bp.y = pack2bf(x0.z, x0.w);
      bp.z = pack2bf(x1.x, x1.y); bp.w = pack2bf(x1.z, x1.w);
    } else {
      bp = *(const uint4*)((const uint16_t*)B + (size_t)z * zsB + (size_t)(n0 + srow) * ldb + (k0 + scol));
    }
    *(uint4*)(&As[srow * LSTR + scol]) = ap;
    *(uint4*)(&Bs[srow * LSTR + scol]) = bp;
    __syncthreads();
    bf16x8 af[2], bfr[2];
#pragma unroll
    for (int x = 0; x < 2; x++) {
      af[x]  = *(const bf16x8*)(&As[(wi * 32 + x * 16 + l15) * LSTR + quad * 8]);
      bfr[x] = *(const bf16x8*)(&Bs[(wj * 32 + x * 16 + l15) * LSTR + quad * 8]);
    }
#pragma unroll
    for (int x = 0; x < 2; x++)
#pragma unroll
      for (int y = 0; y < 2; y++)
        acc[x][y] = MFMA(af[x], bfr[y], acc[x][y]);
    __syncthreads();
  }
#pragma unroll
  for (int x = 0; x < 2; x++)
#pragma unroll
    for (int y = 0; y < 2; y++) {
      const int j = n0 + wj * 32 + y * 16 + l15;
      const float bval = hasBias ? bias[j] : 0.0f;
      const int ib = m0 + wi * 32 + x * 16 + quad * 4;
#pragma unroll
      for (int r = 0; r < 4; r++)
        C[(size_t)z * zsC + (size_t)(ib + r) * ldc + j] = acc[x][y][r] + bval;
    }
}

// ---------------- fused projections (round 3, unchanged) ----------------
__global__ __launch_bounds__(256) void proj_kernel(
    const float* __restrict__ X, const float* __restrict__ emb,
    const float* __restrict__ wq, const float* __restrict__ bq,
    const float* __restrict__ wk, const float* __restrict__ bk,
    const float* __restrict__ wv, const float* __restrict__ bv,
    const float* __restrict__ wrk, const float* __restrict__ brk,
    const float* __restrict__ wrq, const float* __restrict__ brq,
    uint16_t* __restrict__ q, uint16_t* __restrict__ k, uint16_t* __restrict__ vT,
    uint16_t* __restrict__ rkE, uint16_t* __restrict__ rqE)
{
  int bid = blockIdx.x;
  const float *A, *B, *bias; uint16_t* C; int mode;
  if (bid < 64)       {            A = X;   B = wq;  bias = bq;  C = q;   mode = 2; }
  else if (bid < 128) { bid -= 64; A = X;   B = wk;  bias = bk;  C = k;   mode = 2; }
  else if (bid < 192) { bid -= 128; A = X;  B = wv;  bias = bv;  C = vT;  mode = 3; }
  else if (bid < 320) { bid -= 192; A = emb; B = wrk; bias = brk; C = rkE; mode = 1; }
  else                { bid -= 320; A = emb; B = wrq; bias = brq; C = rqE; mode = 1; }
  const int m0 = (bid >> 3) * 64, n0 = (bid & 7) * 64;

  __shared__ __align__(16) uint16_t As[64 * LSTR];
  __shared__ __align__(16) uint16_t Bs[64 * LSTR];
  const int t = threadIdx.x, lane = t & 63, wave = t >> 6;
  const int wi = wave & 1, wj = wave >> 1;
  const int quad = lane >> 4, l15 = lane & 15;
  const int srow = t >> 2, scol = (t & 3) * 8;

  f32x4 acc[2][2] = {};
  for (int k0 = 0; k0 < 512; k0 += 32) {
    const float* Af = A + (size_t)(m0 + srow) * 512 + (k0 + scol);
    const float* Bf = B + (size_t)(n0 + srow) * 512 + (k0 + scol);
    float4 a0 = *(const float4*)(Af), a1 = *(const float4*)(Af + 4);
    float4 b0 = *(const float4*)(Bf), b1 = *(const float4*)(Bf + 4);
    uint4 ap, bp;
    ap.x = pack2bf(a0.x, a0.y); ap.y = pack2bf(a0.z, a0.w);
    ap.z = pack2bf(a1.x, a1.y); ap.w = pack2bf(a1.z, a1.w);
    bp.x = pack2bf(b0.x, b0.y); bp.y = pack2bf(b0.z, b0.w);
    bp.z = pack2bf(b1.x, b1.y); bp.w = pack2bf(b1.z, b1.w);
    *(uint4*)(&As[srow * LSTR + scol]) = ap;
    *(uint4*)(&Bs[srow * LSTR + scol]) = bp;
    __syncthreads();
    bf16x8 af[2], bfr[2];
#pragma unroll
    for (int x = 0; x < 2; x++) {
      af[x]  = *(const bf16x8*)(&As[(wi * 32 + x * 16 + l15) * LSTR + quad * 8]);
      bfr[x] = *(const bf16x8*)(&Bs[(wj * 32 + x * 16 + l15) * LSTR + quad * 8]);
    }
#pragma unroll
    for (int x = 0; x < 2; x++)
#pragma unroll
      for (int y = 0; y < 2; y++)
        acc[x][y] = MFMA(af[x], bfr[y], acc[x][y]);
    __syncthreads();
  }
#pragma unroll
  for (int x = 0; x < 2; x++)
#pragma unroll
    for (int y = 0; y < 2; y++) {
      const int j = n0 + wj * 32 + y * 16 + l15;
      const float bval = bias[j];
      const int ib = m0 + wi * 32 + x * 16 + quad * 4;
#pragma unroll
      for (int r = 0; r < 4; r++) {
        const int i = ib + r;
        size_t off;
        if (mode == 1)      off = (size_t)i * 512 + j;
        else if (mode == 2) off = (size_t)(j >> 6) * 32768 + (size_t)i * 64 + (size_t)(j & 63);
        else                off = (size_t)(j >> 6) * 32768 + (size_t)(j & 63) * 512 + (size_t)i;
        C[off] = f2bf(acc[x][y][r] + bval);
      }
    }
}

// ---------------- fused scores + softmax + PV ----------------
// Block (i-tile, h): rows i0..i0+63, all 512 j. Wave w owns i-rows w*16..+15.
// Per j-tile: S1 = q k_t^T, U2 = q rk_band^T (64x128), U3 = rq_band k_t^T
// (128x64); score(ii,jj) = S1 + U2[ii, jj-ii+63] + U3[jj-ii+63, jj], band
// base e = j0-i0+449 (e in [1,1023], clamped staging). Scores in VGPRs
// (sc[8][4] f32x4 = 128/lane). Softmax via 16-lane shuffles. PV: P tile ->
// wave-private LDS (A-frag layout), vT B-frags straight from global.
__global__ __launch_bounds__(256, 1) void attn_fused_kernel(
    const uint16_t* __restrict__ q, const uint16_t* __restrict__ k,
    const uint16_t* __restrict__ rkE, const uint16_t* __restrict__ rqE,
    const uint16_t* __restrict__ vT,
    float* __restrict__ attn, uint16_t* __restrict__ ctx_bf)
{
  __shared__ __align__(16) char smem[85504];
  uint16_t* qs  = (uint16_t*)smem;            // [64][SSTR]
  uint16_t* stg = (uint16_t*)(smem + 9216);   // [320][SSTR]: k 0-63, rq 64-191, rk 192-319
  float* U2 = (float*)(smem + 9216);          // [64][130]  (aliases stg)
  float* U3 = U2 + 64 * 130;                  // [128][66]
  uint16_t* Pb = (uint16_t*)(smem + 76288);   // [4][16][SSTR] wave-private P tiles

  const int h = blockIdx.y, i0 = blockIdx.x * 64;
  const int t = threadIdx.x, lane = t & 63, w = t >> 6;
  const int quad = lane >> 4, l15 = lane & 15;

  // stage q tile (persistent)
#pragma unroll
  for (int c = 0; c < 2; c++) {
    const int idx = t + c * 256, row = idx >> 3, col = (idx & 7) * 8;
    *(uint4*)(&qs[row * SSTR + col]) =
        *(const uint4*)(q + (size_t)h * 32768 + (size_t)(i0 + row) * 64 + col);
  }

  f32x4 sc[8][4];
#pragma unroll
  for (int jt = 0; jt < 8; jt++) {
    const int j0 = jt * 64;
    const int ebase = j0 - i0 + 449;  // in [1, 897]
    __syncthreads();  // prior U2/U3 reads done (and q-stage visible on jt=0)
#pragma unroll
    for (int c = 0; c < 10; c++) {
      const int idx = t + c * 256, row = idx >> 3, col = (idx & 7) * 8;
      const uint16_t* src;
      if (row < 64)       src = k   + (size_t)h * 32768 + (size_t)(j0 + row) * 64 + col;
      else if (row < 192) src = rqE + (size_t)min(ebase + row - 64, 1023) * 512 + h * 64 + col;
      else                src = rkE + (size_t)min(ebase + row - 192, 1023) * 512 + h * 64 + col;
      *(uint4*)(&stg[row * SSTR + col]) = *(const uint4*)src;
    }
    __syncthreads();

    f32x4 acc1[4] = {}, acc2[8] = {}, acc3[2][4] = {};
#pragma unroll
    for (int s = 0; s < 2; s++) {
      const int ko = s * 32 + quad * 8;
      bf16x8 aq = *(const bf16x8*)(&qs[(w * 16 + l15) * SSTR + ko]);
      bf16x8 bk[4], arq[2], brk[8];
#pragma unroll
      for (int tt = 0; tt < 4; tt++) bk[tt]  = *(const bf16x8*)(&stg[(tt * 16 + l15) * SSTR + ko]);
#pragma unroll
      for (int x = 0; x < 2; x++)    arq[x]  = *(const bf16x8*)(&stg[(64 + w * 32 + x * 16 + l15) * SSTR + ko]);
#pragma unroll
      for (int tt = 0; tt < 8; tt++) brk[tt] = *(const bf16x8*)(&stg[(192 + tt * 16 + l15) * SSTR + ko]);
#pragma unroll
      for (int tt = 0; tt < 4; tt++) acc1[tt] = MFMA(aq, bk[tt], acc1[tt]);
#pragma unroll
      for (int tt = 0; tt < 8; tt++) acc2[tt] = MFMA(aq, brk[tt], acc2[tt]);
#pragma unroll
      for (int x = 0; x < 2; x++)
#pragma unroll
        for (int tt = 0; tt < 4; tt++) acc3[x][tt] = MFMA(arq[x], bk[tt], acc3[x][tt]);
    }
    __syncthreads();  // stg frag reads done before U2/U3 overwrite
#pragma unroll
    for (int tt = 0; tt < 8; tt++)
#pragma unroll
      for (int r = 0; r < 4; r++)
        U2[(w * 16 + quad * 4 + r) * 130 + tt * 16 + l15] = acc2[tt][r];
#pragma unroll
    for (int x = 0; x < 2; x++)
#pragma unroll
      for (int tt = 0; tt < 4; tt++)
#pragma unroll
        for (int r = 0; r < 4; r++)
          U3[(w * 32 + x * 16 + quad * 4 + r) * 66 + tt * 16 + l15] = acc3[x][tt][r];
    __syncthreads();
#pragma unroll
    for (int tt = 0; tt < 4; tt++)
#pragma unroll
      for (int r = 0; r < 4; r++) {
        const int ii = w * 16 + quad * 4 + r, jj = tt * 16 + l15;
        const int rb = jj - ii + 63;
        sc[jt][tt][r] = (acc1[tt][r] + U2[ii * 130 + rb] + U3[rb * 66 + jj]) * 0.125f;
      }
  }

  // softmax over j (per lane: rows quad*4+r of wave slice; cols across l15)
#pragma unroll
  for (int r = 0; r < 4; r++) {
    float m = -1e30f;
#pragma unroll
    for (int jt = 0; jt < 8; jt++)
#pragma unroll
      for (int tt = 0; tt < 4; tt++) m = fmaxf(m, sc[jt][tt][r]);
#pragma unroll
    for (int o = 1; o < 16; o <<= 1) m = fmaxf(m, __shfl_xor(m, o, 64));
    float sum = 0.f;
#pragma unroll
    for (int jt = 0; jt < 8; jt++)
#pragma unroll
      for (int tt = 0; tt < 4; tt++) {
        const float p = __expf(sc[jt][tt][r] - m);
        sc[jt][tt][r] = p; sum += p;
      }
#pragma unroll
    for (int o = 1; o < 16; o <<= 1) sum += __shfl_xor(sum, o, 64);
    const float inv = 1.0f / sum;
#pragma unroll
    for (int jt = 0; jt < 8; jt++)
#pragma unroll
      for (int tt = 0; tt < 4; tt++) sc[jt][tt][r] *= inv;
  }

  // write attn (fp32, d_out)
#pragma unroll
  for (int jt = 0; jt < 8; jt++)
#pragma unroll
    for (int tt = 0; tt < 4; tt++)
#pragma unroll
      for (int r = 0; r < 4; r++)
        attn[((size_t)h * 512 + i0 + w * 16 + quad * 4 + r) * 512 + jt * 64 + tt * 16 + l15]
            = sc[jt][tt][r];

  // PV: ctx_tile[64 i][64 d] = P[64 i][512 j] * v_h[512 j][64 d]
  f32x4 apv[4] = {};
  uint16_t* Pw = Pb + w * 16 * SSTR;
#pragma unroll
  for (int jt = 0; jt < 8; jt++) {
    __syncthreads();  // WAR: prior jt's P reads done before overwrite
#pragma unroll
    for (int tt = 0; tt < 4; tt++)
#pragma unroll
      for (int r = 0; r < 4; r++)
        Pw[(quad * 4 + r) * SSTR + tt * 16 + l15] = f2bf(sc[jt][tt][r]);
    __syncthreads();  // RAW: P visible before A-frag reads
#pragma unroll
    for (int s = 0; s < 2; s++) {
      const int ko = s * 32 + quad * 8;
      bf16x8 aP = *(const bf16x8*)(&Pw[l15 * SSTR + ko]);
#pragma unroll
      for (int tt = 0; tt < 4; tt++) {
        bf16x8 bv = *(const bf16x8*)(vT + (size_t)h * 32768 + (size_t)(tt * 16 + l15) * 512
                                     + jt * 64 + ko);
        apv[tt] = MFMA(aP, bv, apv[tt]);
      }
    }
  }
#pragma unroll
  for (int tt = 0; tt < 4; tt++)
#pragma unroll
    for (int r = 0; r < 4; r++)
      ctx_bf[(size_t)(i0 + w * 16 + quad * 4 + r) * 512 + h * 64 + tt * 16 + l15]
          = f2bf(apv[tt][r]);
}

extern "C" void kernel_launch(void* const* d_in, const int* in_sizes, int n_in,
                              void* d_out, int out_size, void* d_ws, size_t ws_size,
                              hipStream_t stream) {
  const float* X   = (const float*)d_in[0];
  const float* emb = (const float*)d_in[1];
  const float* wq  = (const float*)d_in[2];
  const float* bq  = (const float*)d_in[3];
  const float* wk  = (const float*)d_in[4];
  const float* bk  = (const float*)d_in[5];
  const float* wv  = (const float*)d_in[6];
  const float* bv  = (const float*)d_in[7];
  const float* wrk = (const float*)d_in[8];
  const float* brk = (const float*)d_in[9];
  const float* wrq = (const float*)d_in[10];
  const float* brq = (const float*)d_in[11];
  const float* wo  = (const float*)d_in[12];
  const float* bo  = (const float*)d_in[13];

  // ws layout (uint16 elems, ~4.2 MB):
  uint16_t* q      = (uint16_t*)d_ws;         // [8][512][64]
  uint16_t* k      = q   + 262144;            // [8][512][64]
  uint16_t* vT     = k   + 262144;            // [8][64][512]
  uint16_t* rkE    = vT  + 262144;            // [1024][512]
  uint16_t* rqE    = rkE + 524288;            // [1024][512]
  uint16_t* ctx_bf = rqE + 524288;            // [512][512]

  float* outp = (float*)d_out;                // [512][512]
  float* attn = (float*)d_out + 262144;       // [8][512][512]

  const dim3 blk(256);
  proj_kernel<<<dim3(448), blk, 0, stream>>>(X, emb, wq, bq, wk, bk, wv, bv,
                                             wrk, brk, wrq, brq, q, k, vT, rkE, rqE);
  attn_fused_kernel<<<dim3(8, 8), blk, 0, stream>>>(q, k, rkE, rqE, vT, attn, ctx_bf);
  gemm_bt_kernel<<<dim3(8, 8, 1), blk, 0, stream>>>(ctx_bf, 512, 0, 0,
                                                    wo, 512, 0, 1,
                                                    bo, 1, outp, 512, 0, 512);
}

// Round 5
// 131.027 us; speedup vs baseline: 1.2721x; 1.2721x over previous
//
#include <hip/hip_runtime.h>
#include <stdint.h>

// HeAttention, MI355X/gfx950 — Round 5: 3 launches, attn re-parallelized.
//   L1 proj: q,k,vT,rkE,rqE projections (round 3, proven).
//   L2 attn_fused: 256 blocks (32 i-strips x 8 heads), 16-row strips, the
//      4 waves split the 8 j-tiles (2 each) with per-wave LDS regions;
//      band-scores + cross-wave softmax + PV with cross-wave ctx reduce.
//   L3 out = ctx * wo^T + bo.
// B=1, S=512, D=512, H=8, hd=64, NE=1024. fp32 I/O, bf16 MFMA internally.

typedef __bf16 bf16_t;
typedef bf16_t bf16x8 __attribute__((ext_vector_type(8)));
typedef float f32x4 __attribute__((ext_vector_type(4)));

__device__ __forceinline__ uint16_t f2bf(float f) {
  union { float f; uint32_t i; } c; c.f = f;
  return (uint16_t)((c.i + 0x7fffu + ((c.i >> 16) & 1u)) >> 16);  // RNE
}
__device__ __forceinline__ uint32_t pack2bf(float lo, float hi) {
  return (uint32_t)f2bf(lo) | ((uint32_t)f2bf(hi) << 16);
}
#define MFMA(a, b, c) __builtin_amdgcn_mfma_f32_16x16x32_bf16((a), (b), (c), 0, 0, 0)

#define LSTR 40   // gemm LDS stride (bf16)
#define SSTR 72   // attn stride (bf16): 144 B rows, 16B-aligned vec loads

// ---------------- generic BT GEMM (out projection) ----------------
__global__ __launch_bounds__(256) void gemm_bt_kernel(
    const void* __restrict__ A, int lda, int zsA, int aF32,
    const void* __restrict__ B, int ldb, int zsB, int bF32,
    const float* __restrict__ bias, int hasBias,
    float* __restrict__ C, int ldc, int zsC, int K)
{
  __shared__ __align__(16) uint16_t As[64 * LSTR];
  __shared__ __align__(16) uint16_t Bs[64 * LSTR];
  const int z = blockIdx.z;
  const int m0 = blockIdx.y * 64, n0 = blockIdx.x * 64;
  const int t = threadIdx.x, lane = t & 63, wave = t >> 6;
  const int wi = wave & 1, wj = wave >> 1;
  const int quad = lane >> 4, l15 = lane & 15;
  const int srow = t >> 2, scol = (t & 3) * 8;

  f32x4 acc[2][2] = {};
  for (int k0 = 0; k0 < K; k0 += 32) {
    uint4 ap, bp;
    if (aF32) {
      const float* Af = (const float*)A + (size_t)z * zsA + (size_t)(m0 + srow) * lda + (k0 + scol);
      float4 x0 = *(const float4*)(Af); float4 x1 = *(const float4*)(Af + 4);
      ap.x = pack2bf(x0.x, x0.y); ap.y = pack2bf(x0.z, x0.w);
      ap.z = pack2bf(x1.x, x1.y); ap.w = pack2bf(x1.z, x1.w);
    } else {
      ap = *(const uint4*)((const uint16_t*)A + (size_t)z * zsA + (size_t)(m0 + srow) * lda + (k0 + scol));
    }
    if (bF32) {
      const float* Bf = (const float*)B + (size_t)z * zsB + (size_t)(n0 + srow) * ldb + (k0 + scol);
      float4 x0 = *(const float4*)(Bf); float4 x1 = *(const float4*)(Bf + 4);
      bp.x = pack2bf(x0.x, x0.y); bp.y = pack2bf(x0.z, x0.w);
      bp.z = pack2bf(x1.x, x1.y); bp.w = pack2bf(x1.z, x1.w);
    } else {
      bp = *(const uint4*)((const uint16_t*)B + (size_t)z * zsB + (size_t)(n0 + srow) * ldb + (k0 + scol));
    }
    *(uint4*)(&As[srow * LSTR + scol]) = ap;
    *(uint4*)(&Bs[srow * LSTR + scol]) = bp;
    __syncthreads();
    bf16x8 af[2], bfr[2];
#pragma unroll
    for (int x = 0; x < 2; x++) {
      af[x]  = *(const bf16x8*)(&As[(wi * 32 + x * 16 + l15) * LSTR + quad * 8]);
      bfr[x] = *(const bf16x8*)(&Bs[(wj * 32 + x * 16 + l15) * LSTR + quad * 8]);
    }
#pragma unroll
    for (int x = 0; x < 2; x++)
#pragma unroll
      for (int y = 0; y < 2; y++)
        acc[x][y] = MFMA(af[x], bfr[y], acc[x][y]);
    __syncthreads();
  }
#pragma unroll
  for (int x = 0; x < 2; x++)
#pragma unroll
    for (int y = 0; y < 2; y++) {
      const int j = n0 + wj * 32 + y * 16 + l15;
      const float bval = hasBias ? bias[j] : 0.0f;
      const int ib = m0 + wi * 32 + x * 16 + quad * 4;
#pragma unroll
      for (int r = 0; r < 4; r++)
        C[(size_t)z * zsC + (size_t)(ib + r) * ldc + j] = acc[x][y][r] + bval;
    }
}

// ---------------- fused projections (round 3, unchanged) ----------------
__global__ __launch_bounds__(256) void proj_kernel(
    const float* __restrict__ X, const float* __restrict__ emb,
    const float* __restrict__ wq, const float* __restrict__ bq,
    const float* __restrict__ wk, const float* __restrict__ bk,
    const float* __restrict__ wv, const float* __restrict__ bv,
    const float* __restrict__ wrk, const float* __restrict__ brk,
    const float* __restrict__ wrq, const float* __restrict__ brq,
    uint16_t* __restrict__ q, uint16_t* __restrict__ k, uint16_t* __restrict__ vT,
    uint16_t* __restrict__ rkE, uint16_t* __restrict__ rqE)
{
  int bid = blockIdx.x;
  const float *A, *B, *bias; uint16_t* C; int mode;
  if (bid < 64)       {            A = X;   B = wq;  bias = bq;  C = q;   mode = 2; }
  else if (bid < 128) { bid -= 64; A = X;   B = wk;  bias = bk;  C = k;   mode = 2; }
  else if (bid < 192) { bid -= 128; A = X;  B = wv;  bias = bv;  C = vT;  mode = 3; }
  else if (bid < 320) { bid -= 192; A = emb; B = wrk; bias = brk; C = rkE; mode = 1; }
  else                { bid -= 320; A = emb; B = wrq; bias = brq; C = rqE; mode = 1; }
  const int m0 = (bid >> 3) * 64, n0 = (bid & 7) * 64;

  __shared__ __align__(16) uint16_t As[64 * LSTR];
  __shared__ __align__(16) uint16_t Bs[64 * LSTR];
  const int t = threadIdx.x, lane = t & 63, wave = t >> 6;
  const int wi = wave & 1, wj = wave >> 1;
  const int quad = lane >> 4, l15 = lane & 15;
  const int srow = t >> 2, scol = (t & 3) * 8;

  f32x4 acc[2][2] = {};
  for (int k0 = 0; k0 < 512; k0 += 32) {
    const float* Af = A + (size_t)(m0 + srow) * 512 + (k0 + scol);
    const float* Bf = B + (size_t)(n0 + srow) * 512 + (k0 + scol);
    float4 a0 = *(const float4*)(Af), a1 = *(const float4*)(Af + 4);
    float4 b0 = *(const float4*)(Bf), b1 = *(const float4*)(Bf + 4);
    uint4 ap, bp;
    ap.x = pack2bf(a0.x, a0.y); ap.y = pack2bf(a0.z, a0.w);
    ap.z = pack2bf(a1.x, a1.y); ap.w = pack2bf(a1.z, a1.w);
    bp.x = pack2bf(b0.x, b0.y); bp.y = pack2bf(b0.z, b0.w);
    bp.z = pack2bf(b1.x, b1.y); bp.w = pack2bf(b1.z, b1.w);
    *(uint4*)(&As[srow * LSTR + scol]) = ap;
    *(uint4*)(&Bs[srow * LSTR + scol]) = bp;
    __syncthreads();
    bf16x8 af[2], bfr[2];
#pragma unroll
    for (int x = 0; x < 2; x++) {
      af[x]  = *(const bf16x8*)(&As[(wi * 32 + x * 16 + l15) * LSTR + quad * 8]);
      bfr[x] = *(const bf16x8*)(&Bs[(wj * 32 + x * 16 + l15) * LSTR + quad * 8]);
    }
#pragma unroll
    for (int x = 0; x < 2; x++)
#pragma unroll
      for (int y = 0; y < 2; y++)
        acc[x][y] = MFMA(af[x], bfr[y], acc[x][y]);
    __syncthreads();
  }
#pragma unroll
  for (int x = 0; x < 2; x++)
#pragma unroll
    for (int y = 0; y < 2; y++) {
      const int j = n0 + wj * 32 + y * 16 + l15;
      const float bval = bias[j];
      const int ib = m0 + wi * 32 + x * 16 + quad * 4;
#pragma unroll
      for (int r = 0; r < 4; r++) {
        const int i = ib + r;
        size_t off;
        if (mode == 1)      off = (size_t)i * 512 + j;
        else if (mode == 2) off = (size_t)(j >> 6) * 32768 + (size_t)i * 64 + (size_t)(j & 63);
        else                off = (size_t)(j >> 6) * 32768 + (size_t)(j & 63) * 512 + (size_t)i;
        C[off] = f2bf(acc[x][y][r] + bval);
      }
    }
}

// ---------------- fused scores + softmax + PV (v2: 256 blocks) ----------------
// Block (i-strip, h): 16 i-rows x 512 j. Wave w owns j-tiles {2w, 2w+1}.
// Per j-tile (per-wave LDS region, 32256 B):
//   rows [0,64): k-tile | [64,144): rq band (80) | [144,224): rk band (80)
//   aliases after staging reads: U2 f32 16x84 @+0, U3 f32 80x68 @+5376 B,
//   P bf16 16xSSTR @+0 (PV), ctx partial f32 16x64 @+8192 B (epilogue).
// score(ii,jj) = S1 + U2[ii, rb] + U3[rb, jj], rb = jj-ii+15 in [0,78];
// band base e = j0-i0+497 (e in [1,1023] used; staging clamped).
__global__ __launch_bounds__(256, 1) void attn_fused_kernel(
    const uint16_t* __restrict__ q, const uint16_t* __restrict__ k,
    const uint16_t* __restrict__ rkE, const uint16_t* __restrict__ rqE,
    const uint16_t* __restrict__ vT,
    float* __restrict__ attn, uint16_t* __restrict__ ctx_bf)
{
  __shared__ __align__(16) char smem[131840];
  // [0,129024): 4 per-wave regions; [129024,131328): qs; [131328,131840): red
  const int h = blockIdx.y, i0 = blockIdx.x * 16;
  const int t = threadIdx.x, lane = t & 63, w = t >> 6;
  const int quad = lane >> 4, l15 = lane & 15;

  uint16_t* stgw = (uint16_t*)smem + w * 16128;     // 224 x SSTR bf16
  float* U2f  = (float*)stgw;                       // 16 x 84
  float* U3f  = (float*)((char*)stgw + 5376);       // 80 x 68
  uint16_t* Pw = stgw;                              // 16 x SSTR
  float* ctxw = (float*)((char*)stgw + 8192);       // 16 x 64
  uint16_t* qs = (uint16_t*)(smem + 129024);        // 16 x SSTR
  float* rmax = (float*)(smem + 131328);            // [4][16]
  float* rsum = rmax + 64;                          // [4][16]

  // stage q strip 16x64 (block-shared; visible after first loop barrier)
  if (t < 128) {
    const int row = t >> 3, col = (t & 7) * 8;
    *(uint4*)(&qs[row * SSTR + col]) =
        *(const uint4*)(q + (size_t)h * 32768 + (size_t)(i0 + row) * 64 + col);
  }

  f32x4 sc[2][4];
  const int jbase = w * 2;
#pragma unroll
  for (int jt2 = 0; jt2 < 2; jt2++) {
    const int j0 = (jbase + jt2) * 64;
    const int ebase = j0 - i0 + 497;   // in [1, 945]
    __syncthreads();                   // WAR vs prior diag reads; qs visibility
#pragma unroll
    for (int c = 0; c < 28; c++) {
      const int idx = lane + c * 64;
      const int row = idx >> 3, col = (idx & 7) * 8;
      const uint16_t* src;
      if (row < 64)       src = k   + (size_t)h * 32768 + (size_t)(j0 + row) * 64 + col;
      else if (row < 144) src = rqE + (size_t)min(ebase + row - 64, 1023) * 512 + h * 64 + col;
      else                src = rkE + (size_t)min(ebase + row - 144, 1023) * 512 + h * 64 + col;
      *(uint4*)(&stgw[row * SSTR + col]) = *(const uint4*)src;
    }
    __syncthreads();

    f32x4 acc1[4] = {}, acc2[5] = {}, acc3[5][4] = {};
#pragma unroll
    for (int s = 0; s < 2; s++) {
      const int ko = s * 32 + quad * 8;
      bf16x8 aq = *(const bf16x8*)(&qs[l15 * SSTR + ko]);
      bf16x8 bk[4], arq[5], brk[5];
#pragma unroll
      for (int tt = 0; tt < 4; tt++) bk[tt]  = *(const bf16x8*)(&stgw[(tt * 16 + l15) * SSTR + ko]);
#pragma unroll
      for (int x = 0; x < 5; x++)    arq[x]  = *(const bf16x8*)(&stgw[(64 + x * 16 + l15) * SSTR + ko]);
#pragma unroll
      for (int x = 0; x < 5; x++)    brk[x]  = *(const bf16x8*)(&stgw[(144 + x * 16 + l15) * SSTR + ko]);
#pragma unroll
      for (int tt = 0; tt < 4; tt++) acc1[tt] = MFMA(aq, bk[tt], acc1[tt]);
#pragma unroll
      for (int x = 0; x < 5; x++)    acc2[x] = MFMA(aq, brk[x], acc2[x]);
#pragma unroll
      for (int x = 0; x < 5; x++)
#pragma unroll
        for (int tt = 0; tt < 4; tt++) acc3[x][tt] = MFMA(arq[x], bk[tt], acc3[x][tt]);
    }
    __syncthreads();   // staging reads done before U2/U3 overwrite
#pragma unroll
    for (int x = 0; x < 5; x++)
#pragma unroll
      for (int r = 0; r < 4; r++)
        U2f[(quad * 4 + r) * 84 + x * 16 + l15] = acc2[x][r];
#pragma unroll
    for (int x = 0; x < 5; x++)
#pragma unroll
      for (int tt = 0; tt < 4; tt++)
#pragma unroll
        for (int r = 0; r < 4; r++)
          U3f[(x * 16 + quad * 4 + r) * 68 + tt * 16 + l15] = acc3[x][tt][r];
    __syncthreads();
#pragma unroll
    for (int tt = 0; tt < 4; tt++)
#pragma unroll
      for (int r = 0; r < 4; r++) {
        const int ii = quad * 4 + r, jj = tt * 16 + l15;
        const int rb = jj - ii + 15;   // [0,78]
        sc[jt2][tt][r] = (acc1[tt][r] + U2f[ii * 84 + rb] + U3f[rb * 68 + jj]) * 0.125f;
      }
  }

  // ---- softmax over j=512 (rows shared across waves) ----
  float mrow[4], srow[4];
#pragma unroll
  for (int r = 0; r < 4; r++) {
    float m = -1e30f;
#pragma unroll
    for (int jt2 = 0; jt2 < 2; jt2++)
#pragma unroll
      for (int tt = 0; tt < 4; tt++) m = fmaxf(m, sc[jt2][tt][r]);
#pragma unroll
    for (int o = 1; o < 16; o <<= 1) m = fmaxf(m, __shfl_xor(m, o, 64));
    mrow[r] = m;
  }
  if (l15 == 0)
#pragma unroll
    for (int r = 0; r < 4; r++) rmax[w * 16 + quad * 4 + r] = mrow[r];
  __syncthreads();
#pragma unroll
  for (int r = 0; r < 4; r++) {
    const int row = quad * 4 + r;
    const float m = fmaxf(fmaxf(rmax[row], rmax[16 + row]), fmaxf(rmax[32 + row], rmax[48 + row]));
    float s = 0.f;
#pragma unroll
    for (int jt2 = 0; jt2 < 2; jt2++)
#pragma unroll
      for (int tt = 0; tt < 4; tt++) {
        const float p = __expf(sc[jt2][tt][r] - m);
        sc[jt2][tt][r] = p; s += p;
      }
#pragma unroll
    for (int o = 1; o < 16; o <<= 1) s += __shfl_xor(s, o, 64);
    srow[r] = s;
  }
  if (l15 == 0)
#pragma unroll
    for (int r = 0; r < 4; r++) rsum[w * 16 + quad * 4 + r] = srow[r];
  __syncthreads();
#pragma unroll
  for (int r = 0; r < 4; r++) {
    const int row = quad * 4 + r;
    const float inv = 1.0f / (rsum[row] + rsum[16 + row] + rsum[32 + row] + rsum[48 + row]);
#pragma unroll
    for (int jt2 = 0; jt2 < 2; jt2++)
#pragma unroll
      for (int tt = 0; tt < 4; tt++) {
        sc[jt2][tt][r] *= inv;
        attn[((size_t)h * 512 + i0 + row) * 512 + (jbase + jt2) * 64 + tt * 16 + l15]
            = sc[jt2][tt][r];
      }
  }

  // ---- PV: wave-partial ctx[16][64] over its 128 j, then cross-wave sum ----
  f32x4 apv[4] = {};
#pragma unroll
  for (int jt2 = 0; jt2 < 2; jt2++) {
    __syncthreads();   // prior P/U reads of this region done
#pragma unroll
    for (int tt = 0; tt < 4; tt++)
#pragma unroll
      for (int r = 0; r < 4; r++)
        Pw[(quad * 4 + r) * SSTR + tt * 16 + l15] = f2bf(sc[jt2][tt][r]);
    __syncthreads();
#pragma unroll
    for (int s = 0; s < 2; s++) {
      const int ko = s * 32 + quad * 8;
      bf16x8 aP = *(const bf16x8*)(&Pw[l15 * SSTR + ko]);
#pragma unroll
      for (int tt = 0; tt < 4; tt++) {
        bf16x8 bv = *(const bf16x8*)(vT + (size_t)h * 32768 + (size_t)(tt * 16 + l15) * 512
                                     + (jbase + jt2) * 64 + ko);
        apv[tt] = MFMA(aP, bv, apv[tt]);
      }
    }
  }
#pragma unroll
  for (int tt = 0; tt < 4; tt++)
#pragma unroll
    for (int r = 0; r < 4; r++)
      ctxw[(quad * 4 + r) * 64 + tt * 16 + l15] = apv[tt][r];
  __syncthreads();
  {
    const int row = t >> 4, col = (t & 15) * 4;
    const size_t off = (size_t)(row * 64 + col) * 4;
    float4 s0 = *(const float4*)(smem + 0 * 32256 + 8192 + off);
    float4 s1 = *(const float4*)(smem + 1 * 32256 + 8192 + off);
    float4 s2 = *(const float4*)(smem + 2 * 32256 + 8192 + off);
    float4 s3 = *(const float4*)(smem + 3 * 32256 + 8192 + off);
    const float c0 = s0.x + s1.x + s2.x + s3.x;
    const float c1 = s0.y + s1.y + s2.y + s3.y;
    const float c2 = s0.z + s1.z + s2.z + s3.z;
    const float c3 = s0.w + s1.w + s2.w + s3.w;
    uint2 pk; pk.x = pack2bf(c0, c1); pk.y = pack2bf(c2, c3);
    *(uint2*)(ctx_bf + (size_t)(i0 + row) * 512 + h * 64 + col) = pk;
  }
}

extern "C" void kernel_launch(void* const* d_in, const int* in_sizes, int n_in,
                              void* d_out, int out_size, void* d_ws, size_t ws_size,
                              hipStream_t stream) {
  const float* X   = (const float*)d_in[0];
  const float* emb = (const float*)d_in[1];
  const float* wq  = (const float*)d_in[2];
  const float* bq  = (const float*)d_in[3];
  const float* wk  = (const float*)d_in[4];
  const float* bk  = (const float*)d_in[5];
  const float* wv  = (const float*)d_in[6];
  const float* bv  = (const float*)d_in[7];
  const float* wrk = (const float*)d_in[8];
  const float* brk = (const float*)d_in[9];
  const float* wrq = (const float*)d_in[10];
  const float* brq = (const float*)d_in[11];
  const float* wo  = (const float*)d_in[12];
  const float* bo  = (const float*)d_in[13];

  // ws layout (uint16 elems, ~4.2 MB):
  uint16_t* q      = (uint16_t*)d_ws;         // [8][512][64]
  uint16_t* k      = q   + 262144;            // [8][512][64]
  uint16_t* vT     = k   + 262144;            // [8][64][512]
  uint16_t* rkE    = vT  + 262144;            // [1024][512]
  uint16_t* rqE    = rkE + 524288;            // [1024][512]
  uint16_t* ctx_bf = rqE + 524288;            // [512][512]

  float* outp = (float*)d_out;                // [512][512]
  float* attn = (float*)d_out + 262144;       // [8][512][512]

  const dim3 blk(256);
  proj_kernel<<<dim3(448), blk, 0, stream>>>(X, emb, wq, bq, wk, bk, wv, bv,
                                             wrk, brk, wrq, brq, q, k, vT, rkE, rqE);
  attn_fused_kernel<<<dim3(32, 8), blk, 0, stream>>>(q, k, rkE, rqE, vT, attn, ctx_bf);
  gemm_bt_kernel<<<dim3(8, 8, 1), blk, 0, stream>>>(ctx_bf, 512, 0, 0,
                                                    wo, 512, 0, 1,
                                                    bo, 1, outp, 512, 0, 512);
}